// Round 12
// baseline (3061.727 us; speedup 1.0000x reference)
//
#include <hip/hip_runtime.h>
#include <hip/hip_bf16.h>

#define H_DIM 2048
#define I_DIM 4096
#define NE 8
#define NT 1024

#define BK 32
#define NS1 (H_DIM / BK)   // 64
#define NS2 (I_DIM / BK)   // 128

typedef __bf16 bf16x8 __attribute__((ext_vector_type(8)));
typedef float f32x4 __attribute__((ext_vector_type(4)));
typedef unsigned short u16x8 __attribute__((ext_vector_type(8)));
typedef unsigned int u32x4 __attribute__((ext_vector_type(4)));

__device__ __forceinline__ unsigned short f2bf(float f) {
  return __builtin_bit_cast(unsigned short, (__bf16)f);
}

#define VMC(N) asm volatile("s_waitcnt vmcnt(" #N ")" ::: "memory")
#define SB() __builtin_amdgcn_sched_barrier(0)
// raw global load, result pinned in a v-quad; volatile asm stay program-ordered
#define GL(D, P) asm volatile("global_load_dwordx4 %0, %1, off" : "=v"(D) : "v"(P) : "memory")

// ---------------- transpose-convert: src [K][N] f32 -> dst [N][K] bf16 ----------------
__global__ __launch_bounds__(256) void tconv_kernel(
    const float* __restrict__ src, unsigned short* __restrict__ dst, int K, int N)
{
  __shared__ float tl[64][65];
  const int k0 = blockIdx.x * 64, n0 = blockIdx.y * 64;
  const size_t eo = (size_t)blockIdx.z * K * N;
  const int tid = threadIdx.x;
#pragma unroll
  for (int i = 0; i < 4; ++i) {
    const int r = i * 16 + (tid >> 4);
    const int c = (tid & 15) * 4;
    const f32x4 v = *(const f32x4*)(src + eo + (size_t)(k0 + r) * N + n0 + c);
    tl[r][c] = v[0]; tl[r][c + 1] = v[1]; tl[r][c + 2] = v[2]; tl[r][c + 3] = v[3];
  }
  __syncthreads();
#pragma unroll
  for (int i = 0; i < 2; ++i) {
    const int cch = i * 256 + tid;
    const int n = cch >> 3, kc = (cch & 7) * 8;
    u16x8 o;
#pragma unroll
    for (int j = 0; j < 8; ++j) o[j] = f2bf(tl[kc + j][n]);
    *(u16x8*)(dst + eo + (size_t)(n0 + n) * K + k0 + kc) = o;
  }
}

// ---------------- router: 1 wave per token ----------------
__global__ __launch_bounds__(256) void router_kernel(
    const float* __restrict__ x, const float* __restrict__ rw,
    float* __restrict__ rs_out, int* __restrict__ expert_of,
    float* __restrict__ score_of, int* __restrict__ counts)
{
  const int lane = threadIdx.x & 63;
  const int wv = threadIdx.x >> 6;
  const int t = blockIdx.x * 4 + wv;
  float acc[NE];
#pragma unroll
  for (int e = 0; e < NE; ++e) acc[e] = 0.f;
  const float* xr = x + (size_t)t * H_DIM;
  for (int h0 = 0; h0 < H_DIM; h0 += 64) {
    const float xv = xr[h0 + lane];
    const float* rwp = rw + (size_t)(h0 + lane) * NE;
    const f32x4 r0 = *(const f32x4*)rwp;
    const f32x4 r1 = *(const f32x4*)(rwp + 4);
#pragma unroll
    for (int e = 0; e < 4; ++e) { acc[e] += xv * r0[e]; acc[e + 4] += xv * r1[e]; }
  }
#pragma unroll
  for (int e = 0; e < NE; ++e) {
    acc[e] += __shfl_xor(acc[e], 32, 64);
    acc[e] += __shfl_xor(acc[e], 16, 64);
    acc[e] += __shfl_xor(acc[e], 8, 64);
    acc[e] += __shfl_xor(acc[e], 4, 64);
    acc[e] += __shfl_xor(acc[e], 2, 64);
    acc[e] += __shfl_xor(acc[e], 1, 64);
  }
  int best = 0; float bv = acc[0];
#pragma unroll
  for (int e = 1; e < NE; ++e) if (acc[e] > bv) { bv = acc[e]; best = e; }
  const float score = 1.f / (1.f + __expf(-bv));
  if (lane < NE) rs_out[(size_t)lane * NT + t] = (lane == best) ? score : 0.f;
  if (lane == 0) {
    expert_of[t] = best;
    score_of[t] = score;
    atomicAdd(&counts[best], 1);
  }
}

// ---------------- offsets ----------------
__global__ void offsets_kernel(const int* __restrict__ counts,
                               int* __restrict__ offsets, int* __restrict__ cursor)
{
  if (threadIdx.x == 0) {
    int run = 0;
#pragma unroll
    for (int e = 0; e < NE; ++e) { offsets[e] = run; run += counts[e]; cursor[e] = 0; }
  }
}

// ---------------- scatter ----------------
__global__ void scatter_kernel(const int* __restrict__ expert_of,
                               const int* __restrict__ offsets,
                               int* __restrict__ cursor, int* __restrict__ perm)
{
  const int t = blockIdx.x * 256 + threadIdx.x;
  const int e = expert_of[t];
  const int p = atomicAdd(&cursor[e], 1);
  perm[offsets[e] + p] = t;
}

// ---------------- gather ----------------
__global__ __launch_bounds__(256) void gather_kernel(
    const float* __restrict__ x, const int* __restrict__ perm,
    const float* __restrict__ score_of, unsigned short* __restrict__ xb,
    unsigned short* __restrict__ xs)
{
  const int b = blockIdx.x;
  const int c = threadIdx.x * 8;
  const int src = perm[b];
  const float s = score_of[src];
  const float* xrow = x + (size_t)b * H_DIM + c;
  const float* srow = x + (size_t)src * H_DIM + c;
  u16x8 vb, vs;
#pragma unroll
  for (int j = 0; j < 8; ++j) {
    vb[j] = f2bf(xrow[j]);
    vs[j] = f2bf(srow[j] * s);
  }
  *(u16x8*)&xb[(size_t)b * H_DIM + c] = vb;
  *(u16x8*)&xs[(size_t)b * H_DIM + c] = vs;
}

// ================= GEMM1R: act = silu(X@Wg) * (X@Wu) — barrier-less =================
// W^T [n][k] bf16: each A-frag = ONE dwordx4 (16B contiguous).  X [t][h]: B-frag
// likewise.  4-set rotating register pipeline, counted vmcnt(18), no LDS, no bars.
__global__ __launch_bounds__(256) void gemm1r_kernel(
    const unsigned short* __restrict__ xs, const unsigned short* __restrict__ xb,
    const unsigned short* __restrict__ gupT, const unsigned short* __restrict__ sgwT,
    const unsigned short* __restrict__ suwT, unsigned short* __restrict__ act_r,
    unsigned short* __restrict__ act_s, const int* __restrict__ counts,
    const int* __restrict__ offsets)
{
  const int e = blockIdx.z;
  int cnt, roff;
  const unsigned short *X, *WgT, *WuT; unsigned short* OUT;
  if (e < NE) {
    cnt = counts[e]; roff = offsets[e];
    X = xs; WgT = gupT + (size_t)e * 2 * I_DIM * H_DIM; WuT = WgT + (size_t)I_DIM * H_DIM;
    OUT = act_r;
  } else {
    cnt = NT; roff = 0; X = xb; WgT = sgwT; WuT = suwT; OUT = act_s;
  }
  const int m0 = blockIdx.x * 64;
  if (m0 >= cnt) return;
  const int n0 = blockIdx.y * 64;

  const int lane = threadIdx.x & 63, w = threadIdx.x >> 6;
  const int q = lane >> 4, l15 = lane & 15;

  const int nrow = n0 + w * 16 + l15;
  const char* wg = (const char*)(WgT + (size_t)nrow * H_DIM + q * 8);
  const char* wu = (const char*)(WuT + (size_t)nrow * H_DIM + q * 8);
  const int mA0 = m0 + 0 * 16 + l15, mA1 = m0 + 1 * 16 + l15;
  const int mA2 = m0 + 2 * 16 + l15, mA3 = m0 + 3 * 16 + l15;
  const char* xa0 = (const char*)(X + (size_t)(mA0 < cnt ? roff + mA0 : roff) * H_DIM + q * 8);
  const char* xa1 = (const char*)(X + (size_t)(mA1 < cnt ? roff + mA1 : roff) * H_DIM + q * 8);
  const char* xa2 = (const char*)(X + (size_t)(mA2 < cnt ? roff + mA2 : roff) * H_DIM + q * 8);
  const char* xa3 = (const char*)(X + (size_t)(mA3 < cnt ? roff + mA3 : roff) * H_DIM + q * 8);

  f32x4 accg[4] = {};
  f32x4 accu[4] = {};

#define ISSUE1(X0, X1, X2, X3, WG, WU, T) do {                           \
  const size_t _o = (size_t)(T) * 64;                                    \
  GL(X0, xa0 + _o); GL(X1, xa1 + _o); GL(X2, xa2 + _o); GL(X3, xa3 + _o);\
  GL(WG, wg + _o);  GL(WU, wu + _o);                                     \
} while (0)

#define COMP1(X0, X1, X2, X3, WG, WU) do {                               \
  const bf16x8 _gf = __builtin_bit_cast(bf16x8, WG);                     \
  const bf16x8 _uf = __builtin_bit_cast(bf16x8, WU);                     \
  const bf16x8 _x0 = __builtin_bit_cast(bf16x8, X0);                     \
  const bf16x8 _x1 = __builtin_bit_cast(bf16x8, X1);                     \
  const bf16x8 _x2 = __builtin_bit_cast(bf16x8, X2);                     \
  const bf16x8 _x3 = __builtin_bit_cast(bf16x8, X3);                     \
  accg[0] = __builtin_amdgcn_mfma_f32_16x16x32_bf16(_gf, _x0, accg[0], 0, 0, 0); \
  accu[0] = __builtin_amdgcn_mfma_f32_16x16x32_bf16(_uf, _x0, accu[0], 0, 0, 0); \
  accg[1] = __builtin_amdgcn_mfma_f32_16x16x32_bf16(_gf, _x1, accg[1], 0, 0, 0); \
  accu[1] = __builtin_amdgcn_mfma_f32_16x16x32_bf16(_uf, _x1, accu[1], 0, 0, 0); \
  accg[2] = __builtin_amdgcn_mfma_f32_16x16x32_bf16(_gf, _x2, accg[2], 0, 0, 0); \
  accu[2] = __builtin_amdgcn_mfma_f32_16x16x32_bf16(_uf, _x2, accu[2], 0, 0, 0); \
  accg[3] = __builtin_amdgcn_mfma_f32_16x16x32_bf16(_gf, _x3, accg[3], 0, 0, 0); \
  accu[3] = __builtin_amdgcn_mfma_f32_16x16x32_bf16(_uf, _x3, accu[3], 0, 0, 0); \
} while (0)

  u32x4 Ax0, Ax1, Ax2, Ax3, Ag, Au;
  u32x4 Bx0, Bx1, Bx2, Bx3, Bg, Bu;
  u32x4 Cx0, Cx1, Cx2, Cx3, Cg, Cu;
  u32x4 Dx0, Dx1, Dx2, Dx3, Dg, Du;

  ISSUE1(Ax0, Ax1, Ax2, Ax3, Ag, Au, 0);
  ISSUE1(Bx0, Bx1, Bx2, Bx3, Bg, Bu, 1);
  ISSUE1(Cx0, Cx1, Cx2, Cx3, Cg, Cu, 2);
  ISSUE1(Dx0, Dx1, Dx2, Dx3, Dg, Du, 3);

  for (int t = 0; t + 7 < NS1; t += 4) {
    VMC(18); SB(); COMP1(Ax0, Ax1, Ax2, Ax3, Ag, Au); ISSUE1(Ax0, Ax1, Ax2, Ax3, Ag, Au, t + 4);
    VMC(18); SB(); COMP1(Bx0, Bx1, Bx2, Bx3, Bg, Bu); ISSUE1(Bx0, Bx1, Bx2, Bx3, Bg, Bu, t + 5);
    VMC(18); SB(); COMP1(Cx0, Cx1, Cx2, Cx3, Cg, Cu); ISSUE1(Cx0, Cx1, Cx2, Cx3, Cg, Cu, t + 6);
    VMC(18); SB(); COMP1(Dx0, Dx1, Dx2, Dx3, Dg, Du); ISSUE1(Dx0, Dx1, Dx2, Dx3, Dg, Du, t + 7);
  }
  VMC(18); SB(); COMP1(Ax0, Ax1, Ax2, Ax3, Ag, Au);
  VMC(12); SB(); COMP1(Bx0, Bx1, Bx2, Bx3, Bg, Bu);
  VMC(6);  SB(); COMP1(Cx0, Cx1, Cx2, Cx3, Cg, Cu);
  VMC(0);  SB(); COMP1(Dx0, Dx1, Dx2, Dx3, Dg, Du);

  // D: row(n) = q*4 + reg, col(m) = l15  [proven r2/r8]
  const int nw = n0 + w * 16 + q * 4;
#pragma unroll
  for (int mf = 0; mf < 4; ++mf) {
    const int m = m0 + mf * 16 + l15;
    if (m < cnt) {
      unsigned short o[4];
#pragma unroll
      for (int r = 0; r < 4; ++r) {
        const float g = accg[mf][r];
        const float u = accu[mf][r];
        o[r] = f2bf(g / (1.f + __expf(-g)) * u);
      }
      uint2 pk;
      pk.x = (unsigned)o[0] | ((unsigned)o[1] << 16);
      pk.y = (unsigned)o[2] | ((unsigned)o[3] << 16);
      *(uint2*)&OUT[(size_t)(roff + m) * I_DIM + nw] = pk;
    }
  }
}

// ================= GEMM2R: out[t] (+)= act @ Wd — barrier-less =================
__global__ __launch_bounds__(256) void gemm2r_kernel(
    const unsigned short* __restrict__ ACT, const unsigned short* __restrict__ wdT_base,
    float* __restrict__ OUT, const int* __restrict__ counts,
    const int* __restrict__ offsets, const int* __restrict__ perm,
    const int accumulate)
{
  const int e = blockIdx.z;
  const int cnt = counts ? counts[e] : NT;
  const int roff = offsets ? offsets[e] : 0;
  const int m0 = blockIdx.x * 64;
  if (m0 >= cnt) return;
  const int n0 = blockIdx.y * 64;
  const unsigned short* WdT = wdT_base + (size_t)e * H_DIM * I_DIM;

  const int lane = threadIdx.x & 63, w = threadIdx.x >> 6;
  const int q = lane >> 4, l15 = lane & 15;

  const int nrow = n0 + w * 16 + l15;
  const char* wd = (const char*)(WdT + (size_t)nrow * I_DIM + q * 8);
  const int mA0 = m0 + 0 * 16 + l15, mA1 = m0 + 1 * 16 + l15;
  const int mA2 = m0 + 2 * 16 + l15, mA3 = m0 + 3 * 16 + l15;
  const char* xa0 = (const char*)(ACT + (size_t)(mA0 < cnt ? roff + mA0 : roff) * I_DIM + q * 8);
  const char* xa1 = (const char*)(ACT + (size_t)(mA1 < cnt ? roff + mA1 : roff) * I_DIM + q * 8);
  const char* xa2 = (const char*)(ACT + (size_t)(mA2 < cnt ? roff + mA2 : roff) * I_DIM + q * 8);
  const char* xa3 = (const char*)(ACT + (size_t)(mA3 < cnt ? roff + mA3 : roff) * I_DIM + q * 8);

  f32x4 acc[4] = {};

#define ISSUE2(X0, X1, X2, X3, WD, T) do {                               \
  const size_t _o = (size_t)(T) * 64;                                    \
  GL(X0, xa0 + _o); GL(X1, xa1 + _o); GL(X2, xa2 + _o); GL(X3, xa3 + _o);\
  GL(WD, wd + _o);                                                       \
} while (0)

#define COMP2(X0, X1, X2, X3, WD) do {                                   \
  const bf16x8 _df = __builtin_bit_cast(bf16x8, WD);                     \
  const bf16x8 _x0 = __builtin_bit_cast(bf16x8, X0);                     \
  const bf16x8 _x1 = __builtin_bit_cast(bf16x8, X1);                     \
  const bf16x8 _x2 = __builtin_bit_cast(bf16x8, X2);                     \
  const bf16x8 _x3 = __builtin_bit_cast(bf16x8, X3);                     \
  acc[0] = __builtin_amdgcn_mfma_f32_16x16x32_bf16(_df, _x0, acc[0], 0, 0, 0); \
  acc[1] = __builtin_amdgcn_mfma_f32_16x16x32_bf16(_df, _x1, acc[1], 0, 0, 0); \
  acc[2] = __builtin_amdgcn_mfma_f32_16x16x32_bf16(_df, _x2, acc[2], 0, 0, 0); \
  acc[3] = __builtin_amdgcn_mfma_f32_16x16x32_bf16(_df, _x3, acc[3], 0, 0, 0); \
} while (0)

  u32x4 Ax0, Ax1, Ax2, Ax3, Ad;
  u32x4 Bx0, Bx1, Bx2, Bx3, Bd;
  u32x4 Cx0, Cx1, Cx2, Cx3, Cd;
  u32x4 Dx0, Dx1, Dx2, Dx3, Dd;

  ISSUE2(Ax0, Ax1, Ax2, Ax3, Ad, 0);
  ISSUE2(Bx0, Bx1, Bx2, Bx3, Bd, 1);
  ISSUE2(Cx0, Cx1, Cx2, Cx3, Cd, 2);
  ISSUE2(Dx0, Dx1, Dx2, Dx3, Dd, 3);

  for (int t = 0; t + 7 < NS2; t += 4) {
    VMC(15); SB(); COMP2(Ax0, Ax1, Ax2, Ax3, Ad); ISSUE2(Ax0, Ax1, Ax2, Ax3, Ad, t + 4);
    VMC(15); SB(); COMP2(Bx0, Bx1, Bx2, Bx3, Bd); ISSUE2(Bx0, Bx1, Bx2, Bx3, Bd, t + 5);
    VMC(15); SB(); COMP2(Cx0, Cx1, Cx2, Cx3, Cd); ISSUE2(Cx0, Cx1, Cx2, Cx3, Cd, t + 6);
    VMC(15); SB(); COMP2(Dx0, Dx1, Dx2, Dx3, Dd); ISSUE2(Dx0, Dx1, Dx2, Dx3, Dd, t + 7);
  }
  VMC(15); SB(); COMP2(Ax0, Ax1, Ax2, Ax3, Ad);
  VMC(10); SB(); COMP2(Bx0, Bx1, Bx2, Bx3, Bd);
  VMC(5);  SB(); COMP2(Cx0, Cx1, Cx2, Cx3, Cd);
  VMC(0);  SB(); COMP2(Dx0, Dx1, Dx2, Dx3, Dd);

  const int nw = n0 + w * 16 + q * 4;
#pragma unroll
  for (int mf = 0; mf < 4; ++mf) {
    const int m = m0 + mf * 16 + l15;
    if (m < cnt) {
      const int t = perm ? perm[roff + m] : m;
      float* orow = OUT + (size_t)t * H_DIM + nw;
      f32x4 v = acc[mf];
      if (accumulate) {
        const f32x4 old = *(const f32x4*)orow;
        v += old;
      }
      *(f32x4*)orow = v;
    }
  }
}

extern "C" void kernel_launch(void* const* d_in, const int* in_sizes, int n_in,
                              void* d_out, int out_size, void* d_ws, size_t ws_size,
                              hipStream_t stream)
{
  const float* x   = (const float*)d_in[0];
  const float* rw  = (const float*)d_in[1];
  const float* gup = (const float*)d_in[2];
  const float* dwn = (const float*)d_in[3];
  const float* sgw = (const float*)d_in[4];
  const float* suw = (const float*)d_in[5];
  const float* sdw = (const float*)d_in[6];
  float* out = (float*)d_out;
  float* rs_out = out + (size_t)NT * H_DIM;   // router_scores [E][T] after out [T][H]

  char* ws = (char*)d_ws;
  int* counts    = (int*)ws;               // 32 B
  int* cursor    = (int*)(ws + 32);        // 32 B
  int* offsets   = (int*)(ws + 64);        // 32 B
  int* expert_of = (int*)(ws + 128);       // 4 KB
  float* score_of = (float*)(ws + 128 + 4096);
  int* perm      = (int*)(ws + 128 + 8192);
  unsigned short* xb    = (unsigned short*)(ws + 16384);        // [T][H]  bf16 (4 MB)
  unsigned short* xs    = xb + (size_t)NT * H_DIM;              // [T][H]  bf16 (4 MB)
  unsigned short* act_r = xs + (size_t)NT * H_DIM;              // [T][I]  bf16 (8 MB)
  unsigned short* act_s = act_r + (size_t)NT * I_DIM;           // [T][I]  bf16 (8 MB)
  unsigned short* gupT  = act_s + (size_t)NT * I_DIM;           // [E][2I][H] 268 MB
  unsigned short* dwnT  = gupT + (size_t)NE * 2 * I_DIM * H_DIM; // [E][H][I] 134 MB
  unsigned short* sgwT  = dwnT + (size_t)NE * H_DIM * I_DIM;    // [I][H] 16.8 MB
  unsigned short* suwT  = sgwT + (size_t)I_DIM * H_DIM;         // [I][H] 16.8 MB
  unsigned short* sdwT  = suwT + (size_t)I_DIM * H_DIM;         // [H][I] 16.8 MB

  hipMemsetAsync(counts, 0, 64, stream);

  // transpose-converts: [K][N] f32 -> [N][K] bf16
  tconv_kernel<<<dim3(H_DIM / 64, 2 * I_DIM / 64, NE), dim3(256), 0, stream>>>(
      gup, gupT, H_DIM, 2 * I_DIM);
  tconv_kernel<<<dim3(I_DIM / 64, H_DIM / 64, NE), dim3(256), 0, stream>>>(
      dwn, dwnT, I_DIM, H_DIM);
  tconv_kernel<<<dim3(H_DIM / 64, I_DIM / 64, 1), dim3(256), 0, stream>>>(
      sgw, sgwT, H_DIM, I_DIM);
  tconv_kernel<<<dim3(H_DIM / 64, I_DIM / 64, 1), dim3(256), 0, stream>>>(
      suw, suwT, H_DIM, I_DIM);
  tconv_kernel<<<dim3(I_DIM / 64, H_DIM / 64, 1), dim3(256), 0, stream>>>(
      sdw, sdwT, I_DIM, H_DIM);

  router_kernel<<<dim3(NT / 4), dim3(256), 0, stream>>>(x, rw, rs_out, expert_of, score_of, counts);
  offsets_kernel<<<dim3(1), dim3(64), 0, stream>>>(counts, offsets, cursor);
  scatter_kernel<<<dim3(NT / 256), dim3(256), 0, stream>>>(expert_of, offsets, cursor, perm);
  gather_kernel<<<dim3(NT), dim3(256), 0, stream>>>(x, perm, score_of, xb, xs);

  gemm1r_kernel<<<dim3(NT / 64, I_DIM / 64, NE + 1), dim3(256), 0, stream>>>(
      xs, xb, gupT, sgwT, suwT, act_r, act_s, counts, offsets);
  gemm2r_kernel<<<dim3(NT / 64, H_DIM / 64, 1), dim3(256), 0, stream>>>(
      act_s, sdwT, out, nullptr, nullptr, nullptr, 0);
  gemm2r_kernel<<<dim3(NT / 64, H_DIM / 64, NE), dim3(256), 0, stream>>>(
      act_r, dwnT, out, counts, offsets, perm, 1);
}

// Round 13
// 2516.407 us; speedup vs baseline: 1.2167x; 1.2167x over previous
//
#include <hip/hip_runtime.h>
#include <hip/hip_bf16.h>

#define H_DIM 2048
#define I_DIM 4096
#define NE 8
#define NT 1024

#define BK 32
#define NS1 (H_DIM / BK)   // 64
#define NS2 (I_DIM / BK)   // 128

typedef __bf16 bf16x8 __attribute__((ext_vector_type(8)));
typedef float f32x4 __attribute__((ext_vector_type(4)));
typedef unsigned short u16x8 __attribute__((ext_vector_type(8)));
typedef unsigned int u32x4 __attribute__((ext_vector_type(4)));

__device__ __forceinline__ unsigned short f2bf(float f) {
  return __builtin_bit_cast(unsigned short, (__bf16)f);
}

#define VMC(N) asm volatile("s_waitcnt vmcnt(" #N ")" ::: "memory")
#define SB() __builtin_amdgcn_sched_barrier(0)
#define GL(D, P) asm volatile("global_load_dwordx4 %0, %1, off" : "=v"(D) : "v"(P) : "memory")

// ---------------- pack: W fp32 [K][N] -> MFMA-native bf16 fragments ----------------
// frag (nt, kt): 1KB = lanes l=q*16+l15, 8 bf16 each: W[kt*32+q*8+j][nt*16+l15]
// dst index: ((nt)*(K/32) + kt)*512 + l*8   -> consecutive kt CONTIGUOUS (wave streams)
__global__ __launch_bounds__(256) void pack_kernel(
    const float* __restrict__ src, unsigned short* __restrict__ dst, int K, int N)
{
  __shared__ float tl[32][257];
  const int k0 = blockIdx.x * 32, n0 = blockIdx.y * 256;
  const size_t eo_s = (size_t)blockIdx.z * K * N;
  const size_t eo_d = (size_t)blockIdx.z * ((size_t)(N / 16) * (K / 32) * 512);
  const int tid = threadIdx.x;
#pragma unroll
  for (int i = 0; i < 8; ++i) {
    const int idx = i * 256 + tid;
    const int r = idx >> 6, c4 = (idx & 63) * 4;
    const f32x4 v = *(const f32x4*)(src + eo_s + (size_t)(k0 + r) * N + n0 + c4);
    tl[r][c4] = v[0]; tl[r][c4 + 1] = v[1]; tl[r][c4 + 2] = v[2]; tl[r][c4 + 3] = v[3];
  }
  __syncthreads();
  const int lane = tid & 63, w = tid >> 6;
  const int q = lane >> 4, l15 = lane & 15;
#pragma unroll
  for (int f = 0; f < 4; ++f) {
    const int ntl = w * 4 + f;
    u16x8 o;
#pragma unroll
    for (int j = 0; j < 8; ++j) o[j] = f2bf(tl[q * 8 + j][ntl * 16 + l15]);
    *(u16x8*)(dst + eo_d + ((size_t)(n0 / 16 + ntl) * (K / 32) + blockIdx.x) * 512 + lane * 8) = o;
  }
}

// ---------------- router: 1 wave per token ----------------
__global__ __launch_bounds__(256) void router_kernel(
    const float* __restrict__ x, const float* __restrict__ rw,
    float* __restrict__ rs_out, int* __restrict__ expert_of,
    float* __restrict__ score_of, int* __restrict__ counts)
{
  const int lane = threadIdx.x & 63;
  const int wv = threadIdx.x >> 6;
  const int t = blockIdx.x * 4 + wv;
  float acc[NE];
#pragma unroll
  for (int e = 0; e < NE; ++e) acc[e] = 0.f;
  const float* xr = x + (size_t)t * H_DIM;
  for (int h0 = 0; h0 < H_DIM; h0 += 64) {
    const float xv = xr[h0 + lane];
    const float* rwp = rw + (size_t)(h0 + lane) * NE;
    const f32x4 r0 = *(const f32x4*)rwp;
    const f32x4 r1 = *(const f32x4*)(rwp + 4);
#pragma unroll
    for (int e = 0; e < 4; ++e) { acc[e] += xv * r0[e]; acc[e + 4] += xv * r1[e]; }
  }
#pragma unroll
  for (int e = 0; e < NE; ++e) {
    acc[e] += __shfl_xor(acc[e], 32, 64);
    acc[e] += __shfl_xor(acc[e], 16, 64);
    acc[e] += __shfl_xor(acc[e], 8, 64);
    acc[e] += __shfl_xor(acc[e], 4, 64);
    acc[e] += __shfl_xor(acc[e], 2, 64);
    acc[e] += __shfl_xor(acc[e], 1, 64);
  }
  int best = 0; float bv = acc[0];
#pragma unroll
  for (int e = 1; e < NE; ++e) if (acc[e] > bv) { bv = acc[e]; best = e; }
  const float score = 1.f / (1.f + __expf(-bv));
  if (lane < NE) rs_out[(size_t)lane * NT + t] = (lane == best) ? score : 0.f;
  if (lane == 0) {
    expert_of[t] = best;
    score_of[t] = score;
    atomicAdd(&counts[best], 1);
  }
}

// ---------------- offsets ----------------
__global__ void offsets_kernel(const int* __restrict__ counts,
                               int* __restrict__ offsets, int* __restrict__ cursor)
{
  if (threadIdx.x == 0) {
    int run = 0;
#pragma unroll
    for (int e = 0; e < NE; ++e) { offsets[e] = run; run += counts[e]; cursor[e] = 0; }
  }
}

// ---------------- scatter ----------------
__global__ void scatter_kernel(const int* __restrict__ expert_of,
                               const int* __restrict__ offsets,
                               int* __restrict__ cursor, int* __restrict__ perm)
{
  const int t = blockIdx.x * 256 + threadIdx.x;
  const int e = expert_of[t];
  const int p = atomicAdd(&cursor[e], 1);
  perm[offsets[e] + p] = t;
}

// ---------------- gather ----------------
__global__ __launch_bounds__(256) void gather_kernel(
    const float* __restrict__ x, const int* __restrict__ perm,
    const float* __restrict__ score_of, unsigned short* __restrict__ xb,
    unsigned short* __restrict__ xs)
{
  const int b = blockIdx.x;
  const int c = threadIdx.x * 8;
  const int src = perm[b];
  const float s = score_of[src];
  const float* xrow = x + (size_t)b * H_DIM + c;
  const float* srow = x + (size_t)src * H_DIM + c;
  u16x8 vb, vs;
#pragma unroll
  for (int j = 0; j < 8; ++j) {
    vb[j] = f2bf(xrow[j]);
    vs[j] = f2bf(srow[j] * s);
  }
  *(u16x8*)&xb[(size_t)b * H_DIM + c] = vb;
  *(u16x8*)&xs[(size_t)b * H_DIM + c] = vs;
}

// ================= GEMM1P: act = silu(X@Wg) * (X@Wu) — packed W, barrier-less =================
// Wave w owns n-tile nt = by*4+w.  W frag = ONE coalesced dwordx4/lane from the packed
// stream (64KB contiguous per wave over the K loop).  X frags per-lane from L2.
__global__ __launch_bounds__(256) void gemm1p_kernel(
    const unsigned short* __restrict__ xs, const unsigned short* __restrict__ xb,
    const unsigned short* __restrict__ gupP, const unsigned short* __restrict__ sgwP,
    const unsigned short* __restrict__ suwP, unsigned short* __restrict__ act_r,
    unsigned short* __restrict__ act_s, const int* __restrict__ counts,
    const int* __restrict__ offsets)
{
  const int e = blockIdx.z;
  int cnt, roff;
  const unsigned short *X; const unsigned short *WPg, *WPu; unsigned short* OUT;
  int ntu_off;
  if (e < NE) {
    cnt = counts[e]; roff = offsets[e];
    X = xs;
    WPg = gupP + (size_t)e * ((size_t)(2 * I_DIM / 16) * NS1 * 512);
    WPu = WPg; ntu_off = I_DIM / 16;          // up = frag-rows 256.. of the same packed array
    OUT = act_r;
  } else {
    cnt = NT; roff = 0; X = xb;
    WPg = sgwP; WPu = suwP; ntu_off = 0;
    OUT = act_s;
  }
  const int m0 = blockIdx.x * 64;
  if (m0 >= cnt) return;
  const int n0 = blockIdx.y * 64;

  const int lane = threadIdx.x & 63, w = threadIdx.x >> 6;
  const int q = lane >> 4, l15 = lane & 15;
  const int nt = blockIdx.y * 4 + w;

  const char* wg = (const char*)(WPg + ((size_t)nt * NS1) * 512 + lane * 8);
  const char* wu = (const char*)(WPu + ((size_t)(nt + ntu_off) * NS1) * 512 + lane * 8);

  const int mA0 = m0 + 0 * 16 + l15, mA1 = m0 + 1 * 16 + l15;
  const int mA2 = m0 + 2 * 16 + l15, mA3 = m0 + 3 * 16 + l15;
  const char* xa0 = (const char*)(X + (size_t)(mA0 < cnt ? roff + mA0 : roff) * H_DIM + q * 8);
  const char* xa1 = (const char*)(X + (size_t)(mA1 < cnt ? roff + mA1 : roff) * H_DIM + q * 8);
  const char* xa2 = (const char*)(X + (size_t)(mA2 < cnt ? roff + mA2 : roff) * H_DIM + q * 8);
  const char* xa3 = (const char*)(X + (size_t)(mA3 < cnt ? roff + mA3 : roff) * H_DIM + q * 8);

  f32x4 accg[4] = {};
  f32x4 accu[4] = {};

#define ISSUE1(X0, X1, X2, X3, WG, WU, T) do {                           \
  const size_t _ox = (size_t)(T) * 64;                                   \
  const size_t _ow = (size_t)(T) * 1024;                                 \
  GL(X0, xa0 + _ox); GL(X1, xa1 + _ox); GL(X2, xa2 + _ox); GL(X3, xa3 + _ox); \
  GL(WG, wg + _ow);  GL(WU, wu + _ow);                                   \
} while (0)

#define COMP1(X0, X1, X2, X3, WG, WU) do {                               \
  const bf16x8 _gf = __builtin_bit_cast(bf16x8, WG);                     \
  const bf16x8 _uf = __builtin_bit_cast(bf16x8, WU);                     \
  const bf16x8 _x0 = __builtin_bit_cast(bf16x8, X0);                     \
  const bf16x8 _x1 = __builtin_bit_cast(bf16x8, X1);                     \
  const bf16x8 _x2 = __builtin_bit_cast(bf16x8, X2);                     \
  const bf16x8 _x3 = __builtin_bit_cast(bf16x8, X3);                     \
  accg[0] = __builtin_amdgcn_mfma_f32_16x16x32_bf16(_gf, _x0, accg[0], 0, 0, 0); \
  accu[0] = __builtin_amdgcn_mfma_f32_16x16x32_bf16(_uf, _x0, accu[0], 0, 0, 0); \
  accg[1] = __builtin_amdgcn_mfma_f32_16x16x32_bf16(_gf, _x1, accg[1], 0, 0, 0); \
  accu[1] = __builtin_amdgcn_mfma_f32_16x16x32_bf16(_uf, _x1, accu[1], 0, 0, 0); \
  accg[2] = __builtin_amdgcn_mfma_f32_16x16x32_bf16(_gf, _x2, accg[2], 0, 0, 0); \
  accu[2] = __builtin_amdgcn_mfma_f32_16x16x32_bf16(_uf, _x2, accu[2], 0, 0, 0); \
  accg[3] = __builtin_amdgcn_mfma_f32_16x16x32_bf16(_gf, _x3, accg[3], 0, 0, 0); \
  accu[3] = __builtin_amdgcn_mfma_f32_16x16x32_bf16(_uf, _x3, accu[3], 0, 0, 0); \
} while (0)

  u32x4 Ax0, Ax1, Ax2, Ax3, Ag, Au;
  u32x4 Bx0, Bx1, Bx2, Bx3, Bg, Bu;
  u32x4 Cx0, Cx1, Cx2, Cx3, Cg, Cu;
  u32x4 Dx0, Dx1, Dx2, Dx3, Dg, Du;

  ISSUE1(Ax0, Ax1, Ax2, Ax3, Ag, Au, 0);
  ISSUE1(Bx0, Bx1, Bx2, Bx3, Bg, Bu, 1);
  ISSUE1(Cx0, Cx1, Cx2, Cx3, Cg, Cu, 2);
  ISSUE1(Dx0, Dx1, Dx2, Dx3, Dg, Du, 3);

  for (int t = 0; t + 7 < NS1; t += 4) {
    VMC(18); SB(); COMP1(Ax0, Ax1, Ax2, Ax3, Ag, Au); ISSUE1(Ax0, Ax1, Ax2, Ax3, Ag, Au, t + 4);
    VMC(18); SB(); COMP1(Bx0, Bx1, Bx2, Bx3, Bg, Bu); ISSUE1(Bx0, Bx1, Bx2, Bx3, Bg, Bu, t + 5);
    VMC(18); SB(); COMP1(Cx0, Cx1, Cx2, Cx3, Cg, Cu); ISSUE1(Cx0, Cx1, Cx2, Cx3, Cg, Cu, t + 6);
    VMC(18); SB(); COMP1(Dx0, Dx1, Dx2, Dx3, Dg, Du); ISSUE1(Dx0, Dx1, Dx2, Dx3, Dg, Du, t + 7);
  }
  VMC(18); SB(); COMP1(Ax0, Ax1, Ax2, Ax3, Ag, Au);
  VMC(12); SB(); COMP1(Bx0, Bx1, Bx2, Bx3, Bg, Bu);
  VMC(6);  SB(); COMP1(Cx0, Cx1, Cx2, Cx3, Cg, Cu);
  VMC(0);  SB(); COMP1(Dx0, Dx1, Dx2, Dx3, Dg, Du);

  // D: row(n) = q*4 + reg, col(m) = l15
  const int nw = n0 + w * 16 + q * 4;
#pragma unroll
  for (int mf = 0; mf < 4; ++mf) {
    const int m = m0 + mf * 16 + l15;
    if (m < cnt) {
      unsigned short o[4];
#pragma unroll
      for (int r = 0; r < 4; ++r) {
        const float g = accg[mf][r];
        const float u = accu[mf][r];
        o[r] = f2bf(g / (1.f + __expf(-g)) * u);
      }
      uint2 pk;
      pk.x = (unsigned)o[0] | ((unsigned)o[1] << 16);
      pk.y = (unsigned)o[2] | ((unsigned)o[3] << 16);
      *(uint2*)&OUT[(size_t)(roff + m) * I_DIM + nw] = pk;
    }
  }
}

// ================= GEMM2P: out[t] (+)= act @ Wd — packed W, barrier-less =================
__global__ __launch_bounds__(256) void gemm2p_kernel(
    const unsigned short* __restrict__ ACT, const unsigned short* __restrict__ wdP_base,
    float* __restrict__ OUT, const int* __restrict__ counts,
    const int* __restrict__ offsets, const int* __restrict__ perm,
    const int accumulate)
{
  const int e = blockIdx.z;
  const int cnt = counts ? counts[e] : NT;
  const int roff = offsets ? offsets[e] : 0;
  const int m0 = blockIdx.x * 64;
  if (m0 >= cnt) return;
  const int n0 = blockIdx.y * 64;
  const unsigned short* WdP = wdP_base + (size_t)e * ((size_t)(H_DIM / 16) * NS2 * 512);

  const int lane = threadIdx.x & 63, w = threadIdx.x >> 6;
  const int q = lane >> 4, l15 = lane & 15;
  const int nt = blockIdx.y * 4 + w;

  const char* wd = (const char*)(WdP + ((size_t)nt * NS2) * 512 + lane * 8);

  const int mA0 = m0 + 0 * 16 + l15, mA1 = m0 + 1 * 16 + l15;
  const int mA2 = m0 + 2 * 16 + l15, mA3 = m0 + 3 * 16 + l15;
  const char* xa0 = (const char*)(ACT + (size_t)(mA0 < cnt ? roff + mA0 : roff) * I_DIM + q * 8);
  const char* xa1 = (const char*)(ACT + (size_t)(mA1 < cnt ? roff + mA1 : roff) * I_DIM + q * 8);
  const char* xa2 = (const char*)(ACT + (size_t)(mA2 < cnt ? roff + mA2 : roff) * I_DIM + q * 8);
  const char* xa3 = (const char*)(ACT + (size_t)(mA3 < cnt ? roff + mA3 : roff) * I_DIM + q * 8);

  f32x4 acc[4] = {};

#define ISSUE2(X0, X1, X2, X3, WD, T) do {                               \
  const size_t _ox = (size_t)(T) * 64;                                   \
  const size_t _ow = (size_t)(T) * 1024;                                 \
  GL(X0, xa0 + _ox); GL(X1, xa1 + _ox); GL(X2, xa2 + _ox); GL(X3, xa3 + _ox); \
  GL(WD, wd + _ow);                                                      \
} while (0)

#define COMP2(X0, X1, X2, X3, WD) do {                                   \
  const bf16x8 _df = __builtin_bit_cast(bf16x8, WD);                     \
  const bf16x8 _x0 = __builtin_bit_cast(bf16x8, X0);                     \
  const bf16x8 _x1 = __builtin_bit_cast(bf16x8, X1);                     \
  const bf16x8 _x2 = __builtin_bit_cast(bf16x8, X2);                     \
  const bf16x8 _x3 = __builtin_bit_cast(bf16x8, X3);                     \
  acc[0] = __builtin_amdgcn_mfma_f32_16x16x32_bf16(_df, _x0, acc[0], 0, 0, 0); \
  acc[1] = __builtin_amdgcn_mfma_f32_16x16x32_bf16(_df, _x1, acc[1], 0, 0, 0); \
  acc[2] = __builtin_amdgcn_mfma_f32_16x16x32_bf16(_df, _x2, acc[2], 0, 0, 0); \
  acc[3] = __builtin_amdgcn_mfma_f32_16x16x32_bf16(_df, _x3, acc[3], 0, 0, 0); \
} while (0)

  u32x4 Ax0, Ax1, Ax2, Ax3, Ad;
  u32x4 Bx0, Bx1, Bx2, Bx3, Bd;
  u32x4 Cx0, Cx1, Cx2, Cx3, Cd;
  u32x4 Dx0, Dx1, Dx2, Dx3, Dd;

  ISSUE2(Ax0, Ax1, Ax2, Ax3, Ad, 0);
  ISSUE2(Bx0, Bx1, Bx2, Bx3, Bd, 1);
  ISSUE2(Cx0, Cx1, Cx2, Cx3, Cd, 2);
  ISSUE2(Dx0, Dx1, Dx2, Dx3, Dd, 3);

  for (int t = 0; t + 7 < NS2; t += 4) {
    VMC(15); SB(); COMP2(Ax0, Ax1, Ax2, Ax3, Ad); ISSUE2(Ax0, Ax1, Ax2, Ax3, Ad, t + 4);
    VMC(15); SB(); COMP2(Bx0, Bx1, Bx2, Bx3, Bd); ISSUE2(Bx0, Bx1, Bx2, Bx3, Bd, t + 5);
    VMC(15); SB(); COMP2(Cx0, Cx1, Cx2, Cx3, Cd); ISSUE2(Cx0, Cx1, Cx2, Cx3, Cd, t + 6);
    VMC(15); SB(); COMP2(Dx0, Dx1, Dx2, Dx3, Dd); ISSUE2(Dx0, Dx1, Dx2, Dx3, Dd, t + 7);
  }
  VMC(15); SB(); COMP2(Ax0, Ax1, Ax2, Ax3, Ad);
  VMC(10); SB(); COMP2(Bx0, Bx1, Bx2, Bx3, Bd);
  VMC(5);  SB(); COMP2(Cx0, Cx1, Cx2, Cx3, Cd);
  VMC(0);  SB(); COMP2(Dx0, Dx1, Dx2, Dx3, Dd);

  const int nw = n0 + w * 16 + q * 4;
#pragma unroll
  for (int mf = 0; mf < 4; ++mf) {
    const int m = m0 + mf * 16 + l15;
    if (m < cnt) {
      const int t = perm ? perm[roff + m] : m;
      float* orow = OUT + (size_t)t * H_DIM + nw;
      f32x4 v = acc[mf];
      if (accumulate) {
        const f32x4 old = *(const f32x4*)orow;
        v += old;
      }
      *(f32x4*)orow = v;
    }
  }
}

extern "C" void kernel_launch(void* const* d_in, const int* in_sizes, int n_in,
                              void* d_out, int out_size, void* d_ws, size_t ws_size,
                              hipStream_t stream)
{
  const float* x   = (const float*)d_in[0];
  const float* rw  = (const float*)d_in[1];
  const float* gup = (const float*)d_in[2];
  const float* dwn = (const float*)d_in[3];
  const float* sgw = (const float*)d_in[4];
  const float* suw = (const float*)d_in[5];
  const float* sdw = (const float*)d_in[6];
  float* out = (float*)d_out;
  float* rs_out = out + (size_t)NT * H_DIM;   // router_scores [E][T] after out [T][H]

  char* ws = (char*)d_ws;
  int* counts    = (int*)ws;               // 32 B
  int* cursor    = (int*)(ws + 32);        // 32 B
  int* offsets   = (int*)(ws + 64);        // 32 B
  int* expert_of = (int*)(ws + 128);       // 4 KB
  float* score_of = (float*)(ws + 128 + 4096);
  int* perm      = (int*)(ws + 128 + 8192);
  unsigned short* xb    = (unsigned short*)(ws + 16384);        // [T][H]  bf16 (4 MB)
  unsigned short* xs    = xb + (size_t)NT * H_DIM;              // [T][H]  bf16 (4 MB)
  unsigned short* act_r = xs + (size_t)NT * H_DIM;              // [T][I]  bf16 (8 MB)
  unsigned short* act_s = act_r + (size_t)NT * I_DIM;           // [T][I]  bf16 (8 MB)
  unsigned short* gupP  = act_s + (size_t)NT * I_DIM;           // packed 268 MB
  unsigned short* dwnP  = gupP + (size_t)NE * 2 * I_DIM * H_DIM; // packed 134 MB
  unsigned short* sgwP  = dwnP + (size_t)NE * H_DIM * I_DIM;    // 16.8 MB
  unsigned short* suwP  = sgwP + (size_t)I_DIM * H_DIM;         // 16.8 MB
  unsigned short* sdwP  = suwP + (size_t)I_DIM * H_DIM;         // 16.8 MB

  hipMemsetAsync(counts, 0, 64, stream);

  // pack weights into MFMA-native fragment streams
  pack_kernel<<<dim3(H_DIM / 32, 2 * I_DIM / 256, NE), dim3(256), 0, stream>>>(
      gup, gupP, H_DIM, 2 * I_DIM);
  pack_kernel<<<dim3(I_DIM / 32, H_DIM / 256, NE), dim3(256), 0, stream>>>(
      dwn, dwnP, I_DIM, H_DIM);
  pack_kernel<<<dim3(H_DIM / 32, I_DIM / 256, 1), dim3(256), 0, stream>>>(
      sgw, sgwP, H_DIM, I_DIM);
  pack_kernel<<<dim3(H_DIM / 32, I_DIM / 256, 1), dim3(256), 0, stream>>>(
      suw, suwP, H_DIM, I_DIM);
  pack_kernel<<<dim3(I_DIM / 32, H_DIM / 256, 1), dim3(256), 0, stream>>>(
      sdw, sdwP, I_DIM, H_DIM);

  router_kernel<<<dim3(NT / 4), dim3(256), 0, stream>>>(x, rw, rs_out, expert_of, score_of, counts);
  offsets_kernel<<<dim3(1), dim3(64), 0, stream>>>(counts, offsets, cursor);
  scatter_kernel<<<dim3(NT / 256), dim3(256), 0, stream>>>(expert_of, offsets, cursor, perm);
  gather_kernel<<<dim3(NT), dim3(256), 0, stream>>>(x, perm, score_of, xb, xs);

  gemm1p_kernel<<<dim3(NT / 64, I_DIM / 64, NE + 1), dim3(256), 0, stream>>>(
      xs, xb, gupP, sgwP, suwP, act_r, act_s, counts, offsets);
  gemm2p_kernel<<<dim3(NT / 64, H_DIM / 64, 1), dim3(256), 0, stream>>>(
      act_s, sdwP, out, nullptr, nullptr, nullptr, 0);
  gemm2p_kernel<<<dim3(NT / 64, H_DIM / 64, NE), dim3(256), 0, stream>>>(
      act_r, dwnP, out, counts, offsets, perm, 1);
}